// Round 5
// baseline (4019.865 us; speedup 1.0000x reference)
//
#include <hip/hip_runtime.h>

typedef __bf16 bf16;
typedef __bf16 bf16x8 __attribute__((ext_vector_type(8)));
typedef __bf16 bf16x4 __attribute__((ext_vector_type(4)));
typedef float  f32x4  __attribute__((ext_vector_type(4)));

#define NLAYER 6
#define DMODEL 1024
#define NHEAD  16
#define DHEAD  64
#define FFDIM  4096
#define BATCH  8
#define SEQLEN 512
#define MTOK   (BATCH * SEQLEN)   // 4096 tokens
#define QKVLD  3072               // fused q|k|v row stride

#define GAS(p) ((const __attribute__((address_space(1))) void*)(p))
#define LAS(p) ((__attribute__((address_space(3))) void*)(p))

// ---------------------------------------------------------------------------
// Dtype detection: scan first 64K 16-bit words of trg. fp32 data -> ~128 words
// whose bf16-exponent bits are all-ones; bf16 N(0,1) data -> 0.
// ---------------------------------------------------------------------------
__global__ __launch_bounds__(256) void kdetect(const unsigned short* __restrict__ w,
                                               int* __restrict__ flag)
{
  __shared__ int cnt;
  if (threadIdx.x == 0) cnt = 0;
  __syncthreads();
  int c = 0;
  for (int i = threadIdx.x; i < 65536; i += 256)
    c += (((w[i] >> 7) & 0xFF) == 0xFF);
  atomicAdd(&cnt, c);
  __syncthreads();
  if (threadIdx.x == 0) *flag = (cnt > 16) ? 1 : 0;
}

__global__ __launch_bounds__(256) void kcvt(const void* __restrict__ src,
                                            bf16* __restrict__ dst, long n,
                                            const int* __restrict__ flag)
{
  long i = (long)blockIdx.x * 256 + threadIdx.x;
  if (i >= n) return;
  if (*flag) dst[i] = (bf16)((const float*)src)[i];
  else       dst[i] = ((const bf16*)src)[i];
}

__global__ __launch_bounds__(256) void kout(const bf16* __restrict__ src,
                                            void* __restrict__ dst, long n,
                                            const int* __restrict__ flag)
{
  long i = (long)blockIdx.x * 256 + threadIdx.x;
  if (i >= n) return;
  if (*flag) ((float*)dst)[i] = (float)src[i];
  else       ((bf16*)dst)[i]  = src[i];
}

// ---------------------------------------------------------------------------
// Batched transpose with fused dtype conversion.
// ---------------------------------------------------------------------------
__global__ __launch_bounds__(256) void ktranspose(
    const void* __restrict__ in, bf16* __restrict__ out,
    int R, int C, int ldin, long ebase, long ibs0, long ibs1, int nb1, long obs,
    const int* __restrict__ flag, int mode)
{
  __shared__ bf16 tile[32][33];
  bool f32in = mode && *flag;
  int z = blockIdx.z;
  long base = ebase + (long)(z / nb1) * ibs0 + (long)(z % nb1) * ibs1;
  bf16* dst = out + (long)z * obs;
  int r0 = blockIdx.x * 32, c0 = blockIdx.y * 32;
  int tx = threadIdx.x, ty = threadIdx.y;
  const float* fp = (const float*)in;
  const bf16*  bp = (const bf16*)in;
#pragma unroll
  for (int i = 0; i < 32; i += 8) {
    long idx = base + (long)(r0 + ty + i) * ldin + (c0 + tx);
    tile[ty + i][tx] = f32in ? (bf16)fp[idx] : bp[idx];
  }
  __syncthreads();
#pragma unroll
  for (int i = 0; i < 32; i += 8)
    dst[(long)(c0 + ty + i) * R + (r0 + tx)] = tile[tx][ty + i];
}

// ---------------------------------------------------------------------------
// Mask -> transposed bf16 bias table: mbT[b][k][q] = mask[b][q][k] ? 0 : -10000
// (bf16 bits; -10000 rounds to 0xC61C = -9984, exp(-9984+s-m) == 0.0f always).
// ---------------------------------------------------------------------------
__global__ __launch_bounds__(256) void kmaskt(const int* __restrict__ mask,
                                              unsigned short* __restrict__ mbT)
{
  __shared__ unsigned short tile[32][33];
  int b = blockIdx.z;
  int q0 = blockIdx.x * 32, k0 = blockIdx.y * 32;
  int tx = threadIdx.x, ty = threadIdx.y;
#pragma unroll
  for (int i = 0; i < 32; i += 8) {
    int m = mask[((long)b * SEQLEN + q0 + ty + i) * SEQLEN + k0 + tx];
    tile[ty + i][tx] = m ? (unsigned short)0 : (unsigned short)0xC61C;
  }
  __syncthreads();
#pragma unroll
  for (int i = 0; i < 32; i += 8)
    mbT[((long)b * SEQLEN + k0 + ty + i) * SEQLEN + q0 + tx] = tile[tx][ty + i];
}

// ---------------------------------------------------------------------------
// Legacy batched NT GEMM (m97 structure) — kept for cross-Q projection.
// ---------------------------------------------------------------------------
template<int BM, int BN, int WM, int WN, bool RELU>
__global__ __launch_bounds__(256) void kgemm_nt(
    const bf16* __restrict__ A, const bf16* __restrict__ B, bf16* __restrict__ C,
    const bf16* __restrict__ bias, int K, int lda, int ldb, int ldc,
    long aB0, long aB1, long bB0, long bB1, long cB0, long cB1,
    int nb1, float scale)
{
  constexpr int TM = BM / WM, TN = BN / WN;
  constexpr int FM = TM / 16, FN = TN / 16;
  __shared__ __align__(16) bf16 At[BM * 64];
  __shared__ __align__(16) bf16 Bt[BN * 64];

  int z = blockIdx.z, z0 = z / nb1, z1 = z % nb1;
  const bf16* Ab = A + z0 * aB0 + z1 * aB1;
  const bf16* Bb = B + z0 * bB0 + z1 * bB1;
  bf16* Cb = C + z0 * cB0 + z1 * cB1;

  int row0 = blockIdx.x * BM, col0 = blockIdx.y * BN;
  int t = threadIdx.x;
  int lane = t & 63, w = t >> 6;
  int wm = w / WN, wn = w % WN;
  int m16 = lane & 15, quad = lane >> 4;

  f32x4 acc[FM][FN];
#pragma unroll
  for (int i = 0; i < FM; i++)
#pragma unroll
    for (int j = 0; j < FN; j++)
      acc[i][j] = f32x4{0.f, 0.f, 0.f, 0.f};

  int sr = t >> 3, sc = (t & 7) * 8;
  const bf16* ga = Ab + (long)(row0 + sr) * lda + sc;
  const bf16* gb = Bb + (long)(col0 + sr) * ldb + sc;

  for (int k0 = 0; k0 < K; k0 += 64) {
#pragma unroll
    for (int i = 0; i < BM / 32; i++)
      __builtin_amdgcn_global_load_lds(GAS(ga + (long)i * 32 * lda + k0),
                                       LAS(&At[t * 8 + i * 2048]), 16, 0, 0);
#pragma unroll
    for (int i = 0; i < BN / 32; i++)
      __builtin_amdgcn_global_load_lds(GAS(gb + (long)i * 32 * ldb + k0),
                                       LAS(&Bt[t * 8 + i * 2048]), 16, 0, 0);
    __syncthreads();
#pragma unroll
    for (int s = 0; s < 2; s++) {
      bf16x8 af[FM], bfr[FN];
#pragma unroll
      for (int i = 0; i < FM; i++)
        af[i] = *(const bf16x8*)&At[(wm * TM + i * 16 + m16) * 64 + s * 32 + quad * 8];
#pragma unroll
      for (int j = 0; j < FN; j++)
        bfr[j] = *(const bf16x8*)&Bt[(wn * TN + j * 16 + m16) * 64 + s * 32 + quad * 8];
#pragma unroll
      for (int i = 0; i < FM; i++)
#pragma unroll
        for (int j = 0; j < FN; j++)
          acc[i][j] = __builtin_amdgcn_mfma_f32_16x16x32_bf16(af[i], bfr[j], acc[i][j], 0, 0, 0);
    }
    __syncthreads();
  }

#pragma unroll
  for (int j = 0; j < FN; j++) {
    int col = col0 + wn * TN + j * 16 + m16;
    float bv = bias ? (float)bias[col] : 0.f;
#pragma unroll
    for (int i = 0; i < FM; i++) {
      int row = row0 + wm * TM + i * 16 + quad * 4;
#pragma unroll
      for (int r = 0; r < 4; r++) {
        float v = acc[i][j][r] * scale + bv;
        if (RELU) v = fmaxf(v, 0.f);
        Cb[(long)(row + r) * ldc + col] = (bf16)v;
      }
    }
  }
}

// ---------------------------------------------------------------------------
// 256x256 NT GEMM, 8 waves (2Mx4N), BK=64.
// Deep pipeline: A double-buffered (64KB) + B TRIPLE-buffered (96KB) = 160KB.
// (unchanged from round 4 — see comments there)
// ---------------------------------------------------------------------------
template<bool RELU, bool F32OUT>
__global__ __launch_bounds__(512, 2) void kgemm256(
    const bf16* __restrict__ A, const bf16* __restrict__ B, void* __restrict__ Cv,
    const bf16* __restrict__ bias, int K, int lda, int ldb, int ldc)
{
  __shared__ __align__(16) bf16 As[2][256 * 64];   // 32KB x2 = 64KB
  __shared__ __align__(16) bf16 Bs[3][256 * 64];   // 32KB x3 = 96KB -> 160KB

  const int t = threadIdx.x;
  const int lane = t & 63;
  const int w = t >> 6, wm = w >> 2, wn = w & 3;   // 2 x 4 waves
  const int m16 = lane & 15, quad = lane >> 4;

  const long zk = (long)blockIdx.z * K;            // K-split offset
  const int row0 = blockIdx.x * 256, col0 = blockIdx.y * 256;

  const int sr = t >> 3;
  const int so = (((t & 7) ^ (sr & 7)) << 3);
  const bf16* ga = A + zk + (long)(row0 + sr) * lda + so;
  const bf16* gb = B + zk + (long)(col0 + sr) * ldb + so;

  f32x4 acc[8][4];
#pragma unroll
  for (int i = 0; i < 8; i++)
#pragma unroll
    for (int j = 0; j < 4; j++) acc[i][j] = f32x4{0.f, 0.f, 0.f, 0.f};

  const int NT = K / 64;

  auto stageA = [&](int tt, int q) {
    int tc = tt < NT ? tt : NT - 1;
    __builtin_amdgcn_global_load_lds(GAS(ga + (long)tc * 64 + (long)q * 64 * lda),
                                     LAS((char*)&As[tt & 1][0] + t * 16 + q * 8192),
                                     16, 0, 0);
  };
  auto stageB = [&](int tt, int q) {
    int tc = tt < NT ? tt : NT - 1;
    __builtin_amdgcn_global_load_lds(GAS(gb + (long)tc * 64 + (long)q * 64 * ldb),
                                     LAS((char*)&Bs[tt % 3][0] + t * 16 + q * 8192),
                                     16, 0, 0);
  };

  stageB(0, 0); stageB(0, 1); stageB(0, 2); stageB(0, 3);
  stageA(0, 0); stageA(0, 2); stageA(0, 1); stageA(0, 3);
  stageB(1, 0); stageB(1, 1); stageB(1, 2); stageB(1, 3);
  asm volatile("s_waitcnt vmcnt(4)" ::: "memory");
  __builtin_amdgcn_s_barrier();

  bf16x8 b0[4], b1[4];
  for (int kt = 0; kt < NT; kt++) {
    const char* Ab = (const char*)&As[kt & 1][0];
    const char* Bb = (const char*)&Bs[kt % 3][0];

    { // ph0: qm=0, s=0
      bf16x8 af[4];
#pragma unroll
      for (int j = 0; j < 4; j++) {
        const int r = wn * 64 + j * 16 + m16;
        b0[j] = *(const bf16x8*)(Bb + r * 128 + ((quad * 16) ^ ((r & 7) << 4)));
      }
#pragma unroll
      for (int i = 0; i < 4; i++) {
        const int r = wm * 128 + i * 16 + m16;
        af[i] = *(const bf16x8*)(Ab + r * 128 + ((quad * 16) ^ ((r & 7) << 4)));
      }
      stageA(kt + 1, 0); stageA(kt + 1, 2);
      __builtin_amdgcn_s_barrier();
      asm volatile("s_waitcnt lgkmcnt(0)" ::: "memory");
      __builtin_amdgcn_sched_barrier(0);
      __builtin_amdgcn_s_setprio(1);
#pragma unroll
      for (int i = 0; i < 4; i++)
#pragma unroll
        for (int j = 0; j < 4; j++)
          acc[i][j] = __builtin_amdgcn_mfma_f32_16x16x32_bf16(af[i], b0[j], acc[i][j], 0, 0, 0);
      __builtin_amdgcn_s_setprio(0);
      __builtin_amdgcn_s_barrier();
    }
    { // ph1: qm=0, s=1
      bf16x8 af[4];
#pragma unroll
      for (int j = 0; j < 4; j++) {
        const int r = wn * 64 + j * 16 + m16;
        b1[j] = *(const bf16x8*)(Bb + r * 128 + ((64 + quad * 16) ^ ((r & 7) << 4)));
      }
#pragma unroll
      for (int i = 0; i < 4; i++) {
        const int r = wm * 128 + i * 16 + m16;
        af[i] = *(const bf16x8*)(Ab + r * 128 + ((64 + quad * 16) ^ ((r & 7) << 4)));
      }
      stageA(kt + 1, 1); stageA(kt + 1, 3);
      __builtin_amdgcn_s_barrier();
      asm volatile("s_waitcnt lgkmcnt(0)" ::: "memory");
      __builtin_amdgcn_sched_barrier(0);
      __builtin_amdgcn_s_setprio(1);
#pragma unroll
      for (int i = 0; i < 4; i++)
#pragma unroll
        for (int j = 0; j < 4; j++)
          acc[i][j] = __builtin_amdgcn_mfma_f32_16x16x32_bf16(af[i], b1[j], acc[i][j], 0, 0, 0);
      __builtin_amdgcn_s_setprio(0);
      asm volatile("s_waitcnt vmcnt(6)" ::: "memory");
      __builtin_amdgcn_s_barrier();
    }
    { // ph2: qm=1, s=0
      bf16x8 af[4];
#pragma unroll
      for (int i = 0; i < 4; i++) {
        const int r = wm * 128 + 64 + i * 16 + m16;
        af[i] = *(const bf16x8*)(Ab + r * 128 + ((quad * 16) ^ ((r & 7) << 4)));
      }
      stageB(kt + 2, 0); stageB(kt + 2, 1);
      __builtin_amdgcn_s_barrier();
      asm volatile("s_waitcnt lgkmcnt(0)" ::: "memory");
      __builtin_amdgcn_sched_barrier(0);
      __builtin_amdgcn_s_setprio(1);
#pragma unroll
      for (int i = 0; i < 4; i++)
#pragma unroll
        for (int j = 0; j < 4; j++)
          acc[4 + i][j] = __builtin_amdgcn_mfma_f32_16x16x32_bf16(af[i], b0[j], acc[4 + i][j], 0, 0, 0);
      __builtin_amdgcn_s_setprio(0);
      __builtin_amdgcn_s_barrier();
    }
    { // ph3: qm=1, s=1
      bf16x8 af[4];
#pragma unroll
      for (int i = 0; i < 4; i++) {
        const int r = wm * 128 + 64 + i * 16 + m16;
        af[i] = *(const bf16x8*)(Ab + r * 128 + ((64 + quad * 16) ^ ((r & 7) << 4)));
      }
      stageB(kt + 2, 2); stageB(kt + 2, 3);
      __builtin_amdgcn_s_barrier();
      asm volatile("s_waitcnt lgkmcnt(0)" ::: "memory");
      __builtin_amdgcn_sched_barrier(0);
      __builtin_amdgcn_s_setprio(1);
#pragma unroll
      for (int i = 0; i < 4; i++)
#pragma unroll
        for (int j = 0; j < 4; j++)
          acc[4 + i][j] = __builtin_amdgcn_mfma_f32_16x16x32_bf16(af[i], b1[j], acc[4 + i][j], 0, 0, 0);
      __builtin_amdgcn_s_setprio(0);
      asm volatile("s_waitcnt vmcnt(6)" ::: "memory");
      __builtin_amdgcn_s_barrier();
    }
  }

  if constexpr (F32OUT) {
    float* Cf = (float*)Cv + (long)blockIdx.z * gridDim.x * 256 * ldc;
#pragma unroll
    for (int j = 0; j < 4; j++) {
      const int col = col0 + wn * 64 + j * 16 + m16;
#pragma unroll
      for (int i = 0; i < 8; i++) {
        const int row = row0 + wm * 128 + i * 16 + quad * 4;
#pragma unroll
        for (int r = 0; r < 4; r++)
          Cf[(long)(row + r) * ldc + col] = acc[i][j][r];
      }
    }
  } else {
    bf16* Cb = (bf16*)Cv;
#pragma unroll
    for (int j = 0; j < 4; j++) {
      const int col = col0 + wn * 64 + j * 16 + m16;
      const float bv = (float)bias[col];
#pragma unroll
      for (int i = 0; i < 8; i++) {
        const int row = row0 + wm * 128 + i * 16 + quad * 4;
#pragma unroll
        for (int r = 0; r < 4; r++) {
          float v = acc[i][j][r] + bv;
          if (RELU) v = fmaxf(v, 0.f);
          Cb[(long)(row + r) * ldc + col] = (bf16)v;
        }
      }
    }
  }
}

// ---------------------------------------------------------------------------
// Fused attention: one block = (head h, q-strip of 128 rows, batch b).
// 512 threads = 8 waves; wave w owns q columns w*16..w*16+15 (swapped QK^T:
// S^T = mfma(K, Q) so lane's column q = lane&15, rows k = 16*mf + quad*4 + r).
// LDS pool (147456 B): [0,16K) Q | [16K,80K) K | [80K,144K) Vt.
//   After QK^T, Q+K space is reused for P half-tiles [128][264] (67.6KB);
//   after PV, Vt space is reused for the O transpose tile [128][72].
// Swizzle: all staged tiles use the kgemm256 pattern (linear global_load_lds
// dest + inverse-XOR-swizzled global source; reads XOR (row&7)<<4).
// Softmax: exact (full 512-k row in regs): scale 1/8, +maskbias (self-attn,
// from pre-transposed mbT[b][k][q]), per-lane serial reduce + shfl_xor 16/32.
// PV: O^ = P @ Vt^T per 32-k chunk; P crosses layouts via LDS (pack 2 bf16
// per ds_write_b32; own-wave rows only).
// ---------------------------------------------------------------------------
template<bool MASKED>
__global__ __launch_bounds__(512, 2) void kattn(
    const bf16* __restrict__ qkv, const bf16* __restrict__ Vtg,
    const unsigned short* __restrict__ mbT, bf16* __restrict__ ob)
{
  __shared__ __align__(16) char pool[147456];
  char* Qsb = pool;
  char* Ksb = pool + 16384;
  char* Vsb = pool + 81920;
  char* Psb = pool;            // P half-tile: overlays Q+K after QK^T
  char* Osb = pool + 81920;    // O tile: overlays Vt after PV

  const int t = threadIdx.x;
  const int lane = t & 63;
  const int w = t >> 6;
  const int m16 = lane & 15, quad = lane >> 4;
  const int h = blockIdx.x, strip = blockIdx.y, b = blockIdx.z;
  const int bh = b * NHEAD + h;
  const long qrow0 = (long)b * SEQLEN + strip * 128;   // global token row of Q/out

  // ---- stage Q (2), K (8), Vt (8) ----
#pragma unroll
  for (int i = 0; i < 2; i++) {
    int L = t + 512 * i, row = L >> 3, oct = t & 7;
    __builtin_amdgcn_global_load_lds(
        GAS(qkv + (qrow0 + row) * QKVLD + h * 64 + ((oct ^ (row & 7)) << 3)),
        LAS(Qsb + L * 16), 16, 0, 0);
  }
#pragma unroll
  for (int i = 0; i < 8; i++) {
    int L = t + 512 * i, row = L >> 3, oct = t & 7;
    __builtin_amdgcn_global_load_lds(
        GAS(qkv + 1024 + ((long)b * SEQLEN + row) * QKVLD + h * 64 + ((oct ^ (row & 7)) << 3)),
        LAS(Ksb + L * 16), 16, 0, 0);
  }
#pragma unroll
  for (int i = 0; i < 8; i++) {
    int L = t + 512 * i, row = L >> 6, c = t & 63;
    __builtin_amdgcn_global_load_lds(
        GAS(Vtg + (long)bh * (DHEAD * SEQLEN) + (long)row * SEQLEN + ((c ^ (row & 7)) << 3)),
        LAS(Vsb + L * 16), 16, 0, 0);
  }
  asm volatile("s_waitcnt vmcnt(8)" ::: "memory");   // Q+K landed; Vt in flight
  __builtin_amdgcn_s_barrier();

  // ---- QK^T (swapped): acc[mf] = S^T rows k=16mf.., col q = m16 ----
  const int qr = w * 16 + m16;
  bf16x8 qf0 = *(const bf16x8*)(Qsb + qr * 128 + ((quad * 16) ^ ((qr & 7) << 4)));
  bf16x8 qf1 = *(const bf16x8*)(Qsb + qr * 128 + ((64 + quad * 16) ^ ((qr & 7) << 4)));

  f32x4 acc[32];
#pragma unroll
  for (int mf = 0; mf < 32; mf++) acc[mf] = f32x4{0.f, 0.f, 0.f, 0.f};
#pragma unroll
  for (int mf = 0; mf < 32; mf++) {
    const int kr = mf * 16 + m16;
    bf16x8 a0 = *(const bf16x8*)(Ksb + kr * 128 + ((quad * 16) ^ ((kr & 7) << 4)));
    bf16x8 a1 = *(const bf16x8*)(Ksb + kr * 128 + ((64 + quad * 16) ^ ((kr & 7) << 4)));
    acc[mf] = __builtin_amdgcn_mfma_f32_16x16x32_bf16(a0, qf0, acc[mf], 0, 0, 0);
    acc[mf] = __builtin_amdgcn_mfma_f32_16x16x32_bf16(a1, qf1, acc[mf], 0, 0, 0);
  }

  // ---- scale + mask + exact softmax over k (rows) for column q = m16 ----
  const int qcol = strip * 128 + w * 16 + m16;
  float mx = -3.0e38f;
#pragma unroll 4
  for (int mf = 0; mf < 32; mf++) {
#pragma unroll
    for (int r = 0; r < 4; r++) {
      float s = acc[mf][r] * 0.125f;
      if (MASKED) {
        int k = mf * 16 + quad * 4 + r;
        unsigned short u = mbT[((long)b * SEQLEN + k) * SEQLEN + qcol];
        s += __builtin_bit_cast(float, (unsigned)u << 16);
      }
      acc[mf][r] = s;
      mx = fmaxf(mx, s);
    }
  }
  mx = fmaxf(mx, __shfl_xor(mx, 16));
  mx = fmaxf(mx, __shfl_xor(mx, 32));
  float sum = 0.f;
#pragma unroll
  for (int mf = 0; mf < 32; mf++)
#pragma unroll
    for (int r = 0; r < 4; r++) {
      float e = __expf(acc[mf][r] - mx);
      acc[mf][r] = e;
      sum += e;
    }
  sum += __shfl_xor(sum, 16);
  sum += __shfl_xor(sum, 32);
  const float inv = 1.f / sum;

  // all waves done reading Q/K LDS; Vt must be resident for PV
  __builtin_amdgcn_s_barrier();
  asm volatile("s_waitcnt vmcnt(0)" ::: "memory");

  // ---- PV in two k-halves: P[128 q][256 k] (+8 pad) through LDS ----
  f32x4 o[4];
#pragma unroll
  for (int nf = 0; nf < 4; nf++) o[nf] = f32x4{0.f, 0.f, 0.f, 0.f};

#pragma unroll
  for (int half = 0; half < 2; half++) {
    if (half) {                     // prior PV reads must retire before overwrite
      asm volatile("s_waitcnt lgkmcnt(0)" ::: "memory");
      __builtin_amdgcn_sched_barrier(0);
      __builtin_amdgcn_s_barrier();
    }
    // write this wave's 16 q-rows of P (pack r-pairs -> b32)
#pragma unroll
    for (int mf2 = 0; mf2 < 16; mf2++) {
      const int mf = half * 16 + mf2;
#pragma unroll
      for (int a = 0; a < 2; a++) {
        bf16 lo = (bf16)(acc[mf][2 * a] * inv);
        bf16 hi = (bf16)(acc[mf][2 * a + 1] * inv);
        unsigned u = ((unsigned)*(unsigned short*)&hi << 16) | *(unsigned short*)&lo;
        *(unsigned*)(Psb + qr * 528 + (mf2 * 16 + quad * 4 + 2 * a) * 2) = u;
      }
    }
    asm volatile("s_waitcnt lgkmcnt(0)" ::: "memory");
    __builtin_amdgcn_sched_barrier(0);
    // PV over this half's 8 chunks of 32 k
#pragma unroll
    for (int kb = 0; kb < 8; kb++) {
      bf16x8 pa = *(const bf16x8*)(Psb + qr * 528 + kb * 64 + quad * 16);
#pragma unroll
      for (int nf = 0; nf < 4; nf++) {
        const int vr = nf * 16 + m16;
        bf16x8 vb = *(const bf16x8*)(Vsb + vr * 1024 +
                      ((half * 512 + kb * 64 + quad * 16) ^ ((vr & 7) << 4)));
        o[nf] = __builtin_amdgcn_mfma_f32_16x16x32_bf16(pa, vb, o[nf], 0, 0, 0);
      }
    }
  }

  // ---- O: acc layout [q=quad*4+r][d=16nf+m16] -> LDS transpose -> coalesced ----
  __builtin_amdgcn_s_barrier();    // all Vt reads done before overwriting Vs
#pragma unroll
  for (int nf = 0; nf < 4; nf++)
#pragma unroll
    for (int r = 0; r < 4; r++)
      *(bf16*)(Osb + (w * 16 + quad * 4 + r) * 144 + (nf * 16 + m16) * 2) = (bf16)o[nf][r];
  asm volatile("s_waitcnt lgkmcnt(0)" ::: "memory");
  __builtin_amdgcn_sched_barrier(0);
#pragma unroll
  for (int i2 = 0; i2 < 2; i2++) {
    const int rowL = t >> 2;
    const int d8 = (t & 3) * 16 + i2 * 8;
    bf16x8 v = *(const bf16x8*)(Osb + rowL * 144 + d8 * 2);
    *(bf16x8*)(ob + (qrow0 + rowL) * DMODEL + h * 64 + d8) = v;
  }
}

// ---------------------------------------------------------------------------
// Split-K reduce + bias + residual add + LayerNorm:
// x = LN(h0 + h1 + bias + x) * g + b  (h0,h1 fp32 partials from kgemm256).
// ---------------------------------------------------------------------------
__global__ __launch_bounds__(256) void kaddln2(
    const float* __restrict__ h0, const float* __restrict__ h1,
    const bf16* __restrict__ bias, bf16* __restrict__ x,
    const bf16* __restrict__ g, const bf16* __restrict__ b)
{
  long row = blockIdx.x;
  const float* h0r = h0 + row * DMODEL;
  const float* h1r = h1 + row * DMODEL;
  bf16* xr = x + row * DMODEL;
  int t = threadIdx.x;
  f32x4 a0 = *(const f32x4*)&h0r[t * 4];
  f32x4 a1 = *(const f32x4*)&h1r[t * 4];
  bf16x4 xv = *(const bf16x4*)&xr[t * 4];
  bf16x4 bi = *(const bf16x4*)&bias[t * 4];
  float v[4]; float s1 = 0.f, s2 = 0.f;
#pragma unroll
  for (int i = 0; i < 4; i++) {
    v[i] = a0[i] + a1[i] + (float)bi[i] + (float)xv[i];
    s1 += v[i]; s2 += v[i] * v[i];
  }
#pragma unroll
  for (int off = 32; off > 0; off >>= 1) {
    s1 += __shfl_down(s1, off);
    s2 += __shfl_down(s2, off);
  }
  __shared__ float r1[4], r2[4];
  if ((t & 63) == 0) { r1[t >> 6] = s1; r2[t >> 6] = s2; }
  __syncthreads();
  s1 = r1[0] + r1[1] + r1[2] + r1[3];
  s2 = r2[0] + r2[1] + r2[2] + r2[3];
  float mean = s1 * (1.f / DMODEL);
  float var  = s2 * (1.f / DMODEL) - mean * mean;
  float rstd = rsqrtf(var + 1e-12f);
  bf16x4 gv = *(const bf16x4*)&g[t * 4];
  bf16x4 bv = *(const bf16x4*)&b[t * 4];
  bf16x4 o;
#pragma unroll
  for (int i = 0; i < 4; i++)
    o[i] = (bf16)(((v[i] - mean) * rstd) * (float)gv[i] + (float)bv[i]);
  *(bf16x4*)&xr[t * 4] = o;
}

// ---------------------------------------------------------------------------
extern "C" void kernel_launch(void* const* d_in, const int* in_sizes, int n_in,
                              void* d_out, int out_size, void* d_ws, size_t ws_size,
                              hipStream_t stream)
{
  (void)in_sizes; (void)n_in; (void)out_size; (void)ws_size;
  const void* trg_r  = d_in[0];
  const void* enc_r  = d_in[1];
  const int*  mask   = (const int*)d_in[2];
  const void* sa_w_r = d_in[3];
  const void* sa_b_r = d_in[4];
  const void* ca_w_r = d_in[5];
  const void* ca_b_r = d_in[6];
  const void* ln_g_r = d_in[7];
  const void* ln_b_r = d_in[8];
  const void* w1_r   = d_in[9];
  const void* b1_r   = d_in[10];
  const void* w2_r   = d_in[11];
  const void* b2_r   = d_in[12];

  const size_t XD = (size_t)MTOK * DMODEL;        // 4,194,304 elements
  char* p = (char*)d_ws;
  int*  flag = (int*)p;       p += 256;
  bf16* pSaB = (bf16*)p;      p += (size_t)NLAYER * 4 * DMODEL * 2;
  bf16* pCaB = (bf16*)p;      p += (size_t)NLAYER * 4 * DMODEL * 2;
  bf16* pLnG = (bf16*)p;      p += (size_t)NLAYER * 3 * DMODEL * 2;
  bf16* pLnB = (bf16*)p;      p += (size_t)NLAYER * 3 * DMODEL * 2;
  bf16* pB1  = (bf16*)p;      p += (size_t)NLAYER * FFDIM * 2;
  bf16* pB2  = (bf16*)p;      p += (size_t)NLAYER * DMODEL * 2;
  p = (char*)d_ws + (1 << 20);                                             // 1MB mark
  bf16* x    = (bf16*)p; p += XD * 2;                                      // 8MB
  bf16* encB = (bf16*)p; p += XD * 2;                                      // 8MB
  bf16* qkv  = (bf16*)p; p += (size_t)MTOK * QKVLD * 2;                    // 24MB
  bf16* ob   = (bf16*)p; p += XD * 2;                                      // 8MB
  bf16* hb   = (bf16*)p; p += XD * 2;                                      // 8MB (spare)
  bf16* Vt   = (bf16*)p; p += (size_t)BATCH * NHEAD * DHEAD * SEQLEN * 2;  // 8MB
  bf16* Wt   = (bf16*)p; p += (size_t)4 * DMODEL * DMODEL * 2;             // 8MB
  bf16* big  = (bf16*)p; p += (size_t)BATCH * NHEAD * SEQLEN * SEQLEN * 2; // 64MB
  unsigned short* mbT = (unsigned short*)p; p += (size_t)BATCH * SEQLEN * SEQLEN * 2; // 4MB
  bf16* ffh  = big;
  (void)hb;
  // fp32 split-K partial buffers (time-share `big`):
  float* Pf  = (float*)big;
  float* PfF = (float*)((char*)big + 33554432);
  const long PZ = (long)MTOK * DMODEL;     // elements per fp32 partial

  const long PD = (long)SEQLEN * DMODEL;   // 524288
  const long VS = (long)DHEAD * SEQLEN;    // 32768
  const long PQ = (long)SEQLEN * QKVLD;    // 1572864
  const long DD = (long)DMODEL * DMODEL;   // 1048576
  (void)PD; (void)PQ;

  // --- dtype detection + input conversion + mask transpose ---
  kdetect<<<1, 256, 0, stream>>>((const unsigned short*)trg_r, flag);
  int nb = (int)((XD + 255) / 256);
  kcvt<<<nb, 256, 0, stream>>>(trg_r, x,    (long)XD, flag);
  kcvt<<<nb, 256, 0, stream>>>(enc_r, encB, (long)XD, flag);
  kcvt<<<96,  256, 0, stream>>>(sa_b_r, pSaB, (long)NLAYER * 4 * DMODEL, flag);
  kcvt<<<96,  256, 0, stream>>>(ca_b_r, pCaB, (long)NLAYER * 4 * DMODEL, flag);
  kcvt<<<72,  256, 0, stream>>>(ln_g_r, pLnG, (long)NLAYER * 3 * DMODEL, flag);
  kcvt<<<72,  256, 0, stream>>>(ln_b_r, pLnB, (long)NLAYER * 3 * DMODEL, flag);
  kcvt<<<96,  256, 0, stream>>>(b1_r,   pB1,  (long)NLAYER * FFDIM,      flag);
  kcvt<<<24,  256, 0, stream>>>(b2_r,   pB2,  (long)NLAYER * DMODEL,     flag);
  dim3 tb(32, 8, 1);
  kmaskt<<<dim3(16, 16, 8), tb, 0, stream>>>(mask, mbT);

  for (int l = 0; l < NLAYER; l++) {
    for (int att = 0; att < 2; att++) {
      const void* Wraw = (att == 0) ? sa_w_r : ca_w_r;
      const bf16* Bv   = ((att == 0) ? pSaB : pCaB) + (size_t)l * 4 * DMODEL;

      // transpose (+convert) 4 weights [K][N] -> Wt[i][N][K]; q|k|v contiguous
      ktranspose<<<dim3(32, 32, 4), tb, 0, stream>>>(
          Wraw, Wt, DMODEL, DMODEL, DMODEL, (long)l * 4 * DD, 0, DD, 4, DD, flag, 1);
      if (att == 0) {
        // fused QKV: [4096,1024] @ [3072,1024]^T -> qkv[4096,3072]
        kgemm256<false, false><<<dim3(16, 12, 1), 512, 0, stream>>>(
            x, Wt, qkv, Bv, 1024, 1024, 1024, QKVLD);
      } else {
        // Q from x (legacy 64x128); K|V fused from enc
        kgemm_nt<64,128,2,2,false><<<dim3(64, 8, 1), 256, 0, stream>>>(
            x, Wt, qkv, Bv, 1024, 1024, 1024, QKVLD, 0,0,0,0,0,0, 1, 1.f);
        kgemm256<false, false><<<dim3(16, 8, 1), 512, 0, stream>>>(
            encB, Wt + DD, qkv + 1024, Bv + 1024, 1024, 1024, 1024, QKVLD);
      }
      // Vt[bh][d][j] = V[bh][j][d]  (before fused attention)
      ktranspose<<<dim3(16, 2, 128), tb, 0, stream>>>(
          qkv + 2048, Vt, SEQLEN, DHEAD, QKVLD, 0, PQ, 64, 16, VS, flag, 0);
      // fused attention: S^T in regs + exact softmax + PV -> ob
      if (att == 0)
        kattn<true><<<dim3(16, 4, 8), 512, 0, stream>>>(qkv, Vt, mbT, ob);
      else
        kattn<false><<<dim3(16, 4, 8), 512, 0, stream>>>(qkv, Vt, nullptr, ob);
      // output projection: split-K=2, fp32 partials into Pf
      kgemm256<false, true><<<dim3(16, 4, 2), 512, 0, stream>>>(
          ob, Wt + 3 * DD, Pf, nullptr, 512, 1024, 1024, 1024);
      // x = LN(P0 + P1 + biasO + x)
      kaddln2<<<dim3(MTOK), 256, 0, stream>>>(Pf, Pf + PZ, Bv + 3 * DMODEL, x,
          pLnG + (size_t)(l * 3 + att) * DMODEL, pLnB + (size_t)(l * 3 + att) * DMODEL);
    }

    // ===================== FFN =====================
    ktranspose<<<dim3(32, 128, 1), tb, 0, stream>>>(
        w1_r, Wt, DMODEL, FFDIM, FFDIM, (long)l * DMODEL * FFDIM, 0, 0, 1, 0, flag, 1);
    kgemm256<true, false><<<dim3(16, 16, 1), 512, 0, stream>>>(
        x, Wt, ffh, pB1 + (size_t)l * FFDIM, 1024, 1024, 1024, 4096);
    ktranspose<<<dim3(128, 32, 1), tb, 0, stream>>>(
        w2_r, Wt, FFDIM, DMODEL, DMODEL, (long)l * FFDIM * DMODEL, 0, 0, 1, 0, flag, 1);
    kgemm256<false, true><<<dim3(16, 4, 2), 512, 0, stream>>>(
        ffh, Wt, PfF, nullptr, 2048, 4096, 4096, 1024);
    kaddln2<<<dim3(MTOK), 256, 0, stream>>>(PfF, PfF + PZ, pB2 + (size_t)l * DMODEL, x,
        pLnG + (size_t)(l * 3 + 2) * DMODEL, pLnB + (size_t)(l * 3 + 2) * DMODEL);
  }

  kout<<<nb, 256, 0, stream>>>(x, d_out, (long)XD, flag);
}

// Round 6
// 2512.496 us; speedup vs baseline: 1.5999x; 1.5999x over previous
//
#include <hip/hip_runtime.h>

typedef __bf16 bf16;
typedef __bf16 bf16x8 __attribute__((ext_vector_type(8)));
typedef __bf16 bf16x4 __attribute__((ext_vector_type(4)));
typedef float  f32x4  __attribute__((ext_vector_type(4)));

#define NLAYER 6
#define DMODEL 1024
#define NHEAD  16
#define DHEAD  64
#define FFDIM  4096
#define BATCH  8
#define SEQLEN 512
#define MTOK   (BATCH * SEQLEN)   // 4096 tokens
#define QKVLD  3072               // fused q|k|v row stride

#define GAS(p) ((const __attribute__((address_space(1))) void*)(p))
#define LAS(p) ((__attribute__((address_space(3))) void*)(p))

// ---------------------------------------------------------------------------
// Dtype detection: scan first 64K 16-bit words of trg. fp32 data -> ~128 words
// whose bf16-exponent bits are all-ones; bf16 N(0,1) data -> 0.
// ---------------------------------------------------------------------------
__global__ __launch_bounds__(256) void kdetect(const unsigned short* __restrict__ w,
                                               int* __restrict__ flag)
{
  __shared__ int cnt;
  if (threadIdx.x == 0) cnt = 0;
  __syncthreads();
  int c = 0;
  for (int i = threadIdx.x; i < 65536; i += 256)
    c += (((w[i] >> 7) & 0xFF) == 0xFF);
  atomicAdd(&cnt, c);
  __syncthreads();
  if (threadIdx.x == 0) *flag = (cnt > 16) ? 1 : 0;
}

__global__ __launch_bounds__(256) void kcvt(const void* __restrict__ src,
                                            bf16* __restrict__ dst, long n,
                                            const int* __restrict__ flag)
{
  long i = (long)blockIdx.x * 256 + threadIdx.x;
  if (i >= n) return;
  if (*flag) dst[i] = (bf16)((const float*)src)[i];
  else       dst[i] = ((const bf16*)src)[i];
}

__global__ __launch_bounds__(256) void kout(const bf16* __restrict__ src,
                                            void* __restrict__ dst, long n,
                                            const int* __restrict__ flag)
{
  long i = (long)blockIdx.x * 256 + threadIdx.x;
  if (i >= n) return;
  if (*flag) ((float*)dst)[i] = (float)src[i];
  else       ((bf16*)dst)[i]  = src[i];
}

// ---------------------------------------------------------------------------
// Batched transpose with fused dtype conversion.
// ---------------------------------------------------------------------------
__global__ __launch_bounds__(256) void ktranspose(
    const void* __restrict__ in, bf16* __restrict__ out,
    int R, int C, int ldin, long ebase, long ibs0, long ibs1, int nb1, long obs,
    const int* __restrict__ flag, int mode)
{
  __shared__ bf16 tile[32][33];
  bool f32in = mode && *flag;
  int z = blockIdx.z;
  long base = ebase + (long)(z / nb1) * ibs0 + (long)(z % nb1) * ibs1;
  bf16* dst = out + (long)z * obs;
  int r0 = blockIdx.x * 32, c0 = blockIdx.y * 32;
  int tx = threadIdx.x, ty = threadIdx.y;
  const float* fp = (const float*)in;
  const bf16*  bp = (const bf16*)in;
#pragma unroll
  for (int i = 0; i < 32; i += 8) {
    long idx = base + (long)(r0 + ty + i) * ldin + (c0 + tx);
    tile[ty + i][tx] = f32in ? (bf16)fp[idx] : bp[idx];
  }
  __syncthreads();
#pragma unroll
  for (int i = 0; i < 32; i += 8)
    dst[(long)(c0 + ty + i) * R + (r0 + tx)] = tile[tx][ty + i];
}

// ---------------------------------------------------------------------------
// Legacy batched NT GEMM (m97 structure) — kept for cross-Q projection.
// ---------------------------------------------------------------------------
template<int BM, int BN, int WM, int WN, bool RELU>
__global__ __launch_bounds__(256) void kgemm_nt(
    const bf16* __restrict__ A, const bf16* __restrict__ B, bf16* __restrict__ C,
    const bf16* __restrict__ bias, int K, int lda, int ldb, int ldc,
    long aB0, long aB1, long bB0, long bB1, long cB0, long cB1,
    int nb1, float scale)
{
  constexpr int TM = BM / WM, TN = BN / WN;
  constexpr int FM = TM / 16, FN = TN / 16;
  __shared__ __align__(16) bf16 At[BM * 64];
  __shared__ __align__(16) bf16 Bt[BN * 64];

  int z = blockIdx.z, z0 = z / nb1, z1 = z % nb1;
  const bf16* Ab = A + z0 * aB0 + z1 * aB1;
  const bf16* Bb = B + z0 * bB0 + z1 * bB1;
  bf16* Cb = C + z0 * cB0 + z1 * cB1;

  int row0 = blockIdx.x * BM, col0 = blockIdx.y * BN;
  int t = threadIdx.x;
  int lane = t & 63, w = t >> 6;
  int wm = w / WN, wn = w % WN;
  int m16 = lane & 15, quad = lane >> 4;

  f32x4 acc[FM][FN];
#pragma unroll
  for (int i = 0; i < FM; i++)
#pragma unroll
    for (int j = 0; j < FN; j++)
      acc[i][j] = f32x4{0.f, 0.f, 0.f, 0.f};

  int sr = t >> 3, sc = (t & 7) * 8;
  const bf16* ga = Ab + (long)(row0 + sr) * lda + sc;
  const bf16* gb = Bb + (long)(col0 + sr) * ldb + sc;

  for (int k0 = 0; k0 < K; k0 += 64) {
#pragma unroll
    for (int i = 0; i < BM / 32; i++)
      __builtin_amdgcn_global_load_lds(GAS(ga + (long)i * 32 * lda + k0),
                                       LAS(&At[t * 8 + i * 2048]), 16, 0, 0);
#pragma unroll
    for (int i = 0; i < BN / 32; i++)
      __builtin_amdgcn_global_load_lds(GAS(gb + (long)i * 32 * ldb + k0),
                                       LAS(&Bt[t * 8 + i * 2048]), 16, 0, 0);
    __syncthreads();
#pragma unroll
    for (int s = 0; s < 2; s++) {
      bf16x8 af[FM], bfr[FN];
#pragma unroll
      for (int i = 0; i < FM; i++)
        af[i] = *(const bf16x8*)&At[(wm * TM + i * 16 + m16) * 64 + s * 32 + quad * 8];
#pragma unroll
      for (int j = 0; j < FN; j++)
        bfr[j] = *(const bf16x8*)&Bt[(wn * TN + j * 16 + m16) * 64 + s * 32 + quad * 8];
#pragma unroll
      for (int i = 0; i < FM; i++)
#pragma unroll
        for (int j = 0; j < FN; j++)
          acc[i][j] = __builtin_amdgcn_mfma_f32_16x16x32_bf16(af[i], bfr[j], acc[i][j], 0, 0, 0);
    }
    __syncthreads();
  }

#pragma unroll
  for (int j = 0; j < FN; j++) {
    int col = col0 + wn * TN + j * 16 + m16;
    float bv = bias ? (float)bias[col] : 0.f;
#pragma unroll
    for (int i = 0; i < FM; i++) {
      int row = row0 + wm * TM + i * 16 + quad * 4;
#pragma unroll
      for (int r = 0; r < 4; r++) {
        float v = acc[i][j][r] * scale + bv;
        if (RELU) v = fmaxf(v, 0.f);
        Cb[(long)(row + r) * ldc + col] = (bf16)v;
      }
    }
  }
}

// ---------------------------------------------------------------------------
// 256x256 NT GEMM, 8 waves (2Mx4N), BK=64.
// Deep pipeline: A double-buffered (64KB) + B TRIPLE-buffered (96KB) = 160KB.
// (unchanged from round 4 — see comments there)
// ---------------------------------------------------------------------------
template<bool RELU, bool F32OUT>
__global__ __launch_bounds__(512, 2) void kgemm256(
    const bf16* __restrict__ A, const bf16* __restrict__ B, void* __restrict__ Cv,
    const bf16* __restrict__ bias, int K, int lda, int ldb, int ldc)
{
  __shared__ __align__(16) bf16 As[2][256 * 64];   // 32KB x2 = 64KB
  __shared__ __align__(16) bf16 Bs[3][256 * 64];   // 32KB x3 = 96KB -> 160KB

  const int t = threadIdx.x;
  const int lane = t & 63;
  const int w = t >> 6, wm = w >> 2, wn = w & 3;   // 2 x 4 waves
  const int m16 = lane & 15, quad = lane >> 4;

  const long zk = (long)blockIdx.z * K;            // K-split offset
  const int row0 = blockIdx.x * 256, col0 = blockIdx.y * 256;

  const int sr = t >> 3;
  const int so = (((t & 7) ^ (sr & 7)) << 3);
  const bf16* ga = A + zk + (long)(row0 + sr) * lda + so;
  const bf16* gb = B + zk + (long)(col0 + sr) * ldb + so;

  f32x4 acc[8][4];
#pragma unroll
  for (int i = 0; i < 8; i++)
#pragma unroll
    for (int j = 0; j < 4; j++) acc[i][j] = f32x4{0.f, 0.f, 0.f, 0.f};

  const int NT = K / 64;

  auto stageA = [&](int tt, int q) {
    int tc = tt < NT ? tt : NT - 1;
    __builtin_amdgcn_global_load_lds(GAS(ga + (long)tc * 64 + (long)q * 64 * lda),
                                     LAS((char*)&As[tt & 1][0] + t * 16 + q * 8192),
                                     16, 0, 0);
  };
  auto stageB = [&](int tt, int q) {
    int tc = tt < NT ? tt : NT - 1;
    __builtin_amdgcn_global_load_lds(GAS(gb + (long)tc * 64 + (long)q * 64 * ldb),
                                     LAS((char*)&Bs[tt % 3][0] + t * 16 + q * 8192),
                                     16, 0, 0);
  };

  stageB(0, 0); stageB(0, 1); stageB(0, 2); stageB(0, 3);
  stageA(0, 0); stageA(0, 2); stageA(0, 1); stageA(0, 3);
  stageB(1, 0); stageB(1, 1); stageB(1, 2); stageB(1, 3);
  asm volatile("s_waitcnt vmcnt(4)" ::: "memory");
  __builtin_amdgcn_s_barrier();

  bf16x8 b0[4], b1[4];
  for (int kt = 0; kt < NT; kt++) {
    const char* Ab = (const char*)&As[kt & 1][0];
    const char* Bb = (const char*)&Bs[kt % 3][0];

    { // ph0: qm=0, s=0
      bf16x8 af[4];
#pragma unroll
      for (int j = 0; j < 4; j++) {
        const int r = wn * 64 + j * 16 + m16;
        b0[j] = *(const bf16x8*)(Bb + r * 128 + ((quad * 16) ^ ((r & 7) << 4)));
      }
#pragma unroll
      for (int i = 0; i < 4; i++) {
        const int r = wm * 128 + i * 16 + m16;
        af[i] = *(const bf16x8*)(Ab + r * 128 + ((quad * 16) ^ ((r & 7) << 4)));
      }
      stageA(kt + 1, 0); stageA(kt + 1, 2);
      __builtin_amdgcn_s_barrier();
      asm volatile("s_waitcnt lgkmcnt(0)" ::: "memory");
      __builtin_amdgcn_sched_barrier(0);
      __builtin_amdgcn_s_setprio(1);
#pragma unroll
      for (int i = 0; i < 4; i++)
#pragma unroll
        for (int j = 0; j < 4; j++)
          acc[i][j] = __builtin_amdgcn_mfma_f32_16x16x32_bf16(af[i], b0[j], acc[i][j], 0, 0, 0);
      __builtin_amdgcn_s_setprio(0);
      __builtin_amdgcn_s_barrier();
    }
    { // ph1: qm=0, s=1
      bf16x8 af[4];
#pragma unroll
      for (int j = 0; j < 4; j++) {
        const int r = wn * 64 + j * 16 + m16;
        b1[j] = *(const bf16x8*)(Bb + r * 128 + ((64 + quad * 16) ^ ((r & 7) << 4)));
      }
#pragma unroll
      for (int i = 0; i < 4; i++) {
        const int r = wm * 128 + i * 16 + m16;
        af[i] = *(const bf16x8*)(Ab + r * 128 + ((64 + quad * 16) ^ ((r & 7) << 4)));
      }
      stageA(kt + 1, 1); stageA(kt + 1, 3);
      __builtin_amdgcn_s_barrier();
      asm volatile("s_waitcnt lgkmcnt(0)" ::: "memory");
      __builtin_amdgcn_sched_barrier(0);
      __builtin_amdgcn_s_setprio(1);
#pragma unroll
      for (int i = 0; i < 4; i++)
#pragma unroll
        for (int j = 0; j < 4; j++)
          acc[i][j] = __builtin_amdgcn_mfma_f32_16x16x32_bf16(af[i], b1[j], acc[i][j], 0, 0, 0);
      __builtin_amdgcn_s_setprio(0);
      asm volatile("s_waitcnt vmcnt(6)" ::: "memory");
      __builtin_amdgcn_s_barrier();
    }
    { // ph2: qm=1, s=0
      bf16x8 af[4];
#pragma unroll
      for (int i = 0; i < 4; i++) {
        const int r = wm * 128 + 64 + i * 16 + m16;
        af[i] = *(const bf16x8*)(Ab + r * 128 + ((quad * 16) ^ ((r & 7) << 4)));
      }
      stageB(kt + 2, 0); stageB(kt + 2, 1);
      __builtin_amdgcn_s_barrier();
      asm volatile("s_waitcnt lgkmcnt(0)" ::: "memory");
      __builtin_amdgcn_sched_barrier(0);
      __builtin_amdgcn_s_setprio(1);
#pragma unroll
      for (int i = 0; i < 4; i++)
#pragma unroll
        for (int j = 0; j < 4; j++)
          acc[4 + i][j] = __builtin_amdgcn_mfma_f32_16x16x32_bf16(af[i], b0[j], acc[4 + i][j], 0, 0, 0);
      __builtin_amdgcn_s_setprio(0);
      __builtin_amdgcn_s_barrier();
    }
    { // ph3: qm=1, s=1
      bf16x8 af[4];
#pragma unroll
      for (int i = 0; i < 4; i++) {
        const int r = wm * 128 + 64 + i * 16 + m16;
        af[i] = *(const bf16x8*)(Ab + r * 128 + ((64 + quad * 16) ^ ((r & 7) << 4)));
      }
      stageB(kt + 2, 2); stageB(kt + 2, 3);
      __builtin_amdgcn_s_barrier();
      asm volatile("s_waitcnt lgkmcnt(0)" ::: "memory");
      __builtin_amdgcn_sched_barrier(0);
      __builtin_amdgcn_s_setprio(1);
#pragma unroll
      for (int i = 0; i < 4; i++)
#pragma unroll
        for (int j = 0; j < 4; j++)
          acc[4 + i][j] = __builtin_amdgcn_mfma_f32_16x16x32_bf16(af[i], b1[j], acc[4 + i][j], 0, 0, 0);
      __builtin_amdgcn_s_setprio(0);
      asm volatile("s_waitcnt vmcnt(6)" ::: "memory");
      __builtin_amdgcn_s_barrier();
    }
  }

  if constexpr (F32OUT) {
    float* Cf = (float*)Cv + (long)blockIdx.z * gridDim.x * 256 * ldc;
#pragma unroll
    for (int j = 0; j < 4; j++) {
      const int col = col0 + wn * 64 + j * 16 + m16;
#pragma unroll
      for (int i = 0; i < 8; i++) {
        const int row = row0 + wm * 128 + i * 16 + quad * 4;
#pragma unroll
        for (int r = 0; r < 4; r++)
          Cf[(long)(row + r) * ldc + col] = acc[i][j][r];
      }
    }
  } else {
    bf16* Cb = (bf16*)Cv;
#pragma unroll
    for (int j = 0; j < 4; j++) {
      const int col = col0 + wn * 64 + j * 16 + m16;
      const float bv = (float)bias[col];
#pragma unroll
      for (int i = 0; i < 8; i++) {
        const int row = row0 + wm * 128 + i * 16 + quad * 4;
#pragma unroll
        for (int r = 0; r < 4; r++) {
          float v = acc[i][j][r] + bv;
          if (RELU) v = fmaxf(v, 0.f);
          Cb[(long)(row + r) * ldc + col] = (bf16)v;
        }
      }
    }
  }
}

// ---------------------------------------------------------------------------
// Fused attention: one block = (head h, q-strip of 128 rows, batch b).
// 512 threads = 8 waves; wave w owns q columns w*16..w*16+15 (swapped QK^T:
// S^T = mfma(K, Q) so lane's column q = lane&15, rows k = 16*mf + quad*4 + r).
// LDS pool (147456 B): [0,16K) Q | [16K,80K) K | [80K,144K) Vt.
//   After QK^T, Q+K space is reused for P half-tiles [128][264] (67.6KB);
//   after PV, Vt space is reused for the O transpose tile [128][72].
// Softmax: exact, fully in registers. ALL acc indexing is compile-time static
// (rule #20: partial unroll put acc[] in scratch in round 5 — 88 VGPR,
// 500MB scratch writes, 174us; full unroll is mandatory).
// Mask: direct int4 loads of mask[b][qcol][k..k+3] (k is the fast axis in the
// S^T layout) — replaces score with -10000 where mask==0 (reference semantics).
// ---------------------------------------------------------------------------
template<bool MASKED>
__global__ __launch_bounds__(512, 2) void kattn(
    const bf16* __restrict__ qkv, const bf16* __restrict__ Vtg,
    const int* __restrict__ mask, bf16* __restrict__ ob)
{
  __shared__ __align__(16) char pool[147456];
  char* Qsb = pool;
  char* Ksb = pool + 16384;
  char* Vsb = pool + 81920;
  char* Psb = pool;            // P half-tile: overlays Q+K after QK^T
  char* Osb = pool + 81920;    // O tile: overlays Vt after PV

  const int t = threadIdx.x;
  const int lane = t & 63;
  const int w = t >> 6;
  const int m16 = lane & 15, quad = lane >> 4;
  const int h = blockIdx.x, strip = blockIdx.y, b = blockIdx.z;
  const int bh = b * NHEAD + h;
  const long qrow0 = (long)b * SEQLEN + strip * 128;   // global token row of Q/out

  // ---- stage Q (2), K (8), Vt (8) ----
#pragma unroll
  for (int i = 0; i < 2; i++) {
    int L = t + 512 * i, row = L >> 3, oct = t & 7;
    __builtin_amdgcn_global_load_lds(
        GAS(qkv + (qrow0 + row) * QKVLD + h * 64 + ((oct ^ (row & 7)) << 3)),
        LAS(Qsb + L * 16), 16, 0, 0);
  }
#pragma unroll
  for (int i = 0; i < 8; i++) {
    int L = t + 512 * i, row = L >> 3, oct = t & 7;
    __builtin_amdgcn_global_load_lds(
        GAS(qkv + 1024 + ((long)b * SEQLEN + row) * QKVLD + h * 64 + ((oct ^ (row & 7)) << 3)),
        LAS(Ksb + L * 16), 16, 0, 0);
  }
#pragma unroll
  for (int i = 0; i < 8; i++) {
    int L = t + 512 * i, row = L >> 6, c = t & 63;
    __builtin_amdgcn_global_load_lds(
        GAS(Vtg + (long)bh * (DHEAD * SEQLEN) + (long)row * SEQLEN + ((c ^ (row & 7)) << 3)),
        LAS(Vsb + L * 16), 16, 0, 0);
  }
  asm volatile("s_waitcnt vmcnt(8)" ::: "memory");   // Q+K landed; Vt in flight
  __builtin_amdgcn_s_barrier();

  // ---- QK^T (swapped): acc[mf] = S^T rows k=16mf.., col q = m16 ----
  const int qr = w * 16 + m16;
  bf16x8 qf0 = *(const bf16x8*)(Qsb + qr * 128 + ((quad * 16) ^ ((qr & 7) << 4)));
  bf16x8 qf1 = *(const bf16x8*)(Qsb + qr * 128 + ((64 + quad * 16) ^ ((qr & 7) << 4)));

  f32x4 acc[32];
#pragma unroll
  for (int mf = 0; mf < 32; mf++) acc[mf] = f32x4{0.f, 0.f, 0.f, 0.f};
#pragma unroll
  for (int mf = 0; mf < 32; mf++) {
    const int kr = mf * 16 + m16;
    bf16x8 a0 = *(const bf16x8*)(Ksb + kr * 128 + ((quad * 16) ^ ((kr & 7) << 4)));
    bf16x8 a1 = *(const bf16x8*)(Ksb + kr * 128 + ((64 + quad * 16) ^ ((kr & 7) << 4)));
    acc[mf] = __builtin_amdgcn_mfma_f32_16x16x32_bf16(a0, qf0, acc[mf], 0, 0, 0);
    acc[mf] = __builtin_amdgcn_mfma_f32_16x16x32_bf16(a1, qf1, acc[mf], 0, 0, 0);
  }

  // ---- scale + mask + exact softmax over k (rows) for column q = m16 ----
  // FULL unroll everywhere: acc[] must be statically indexed (rule #20).
  const int qcol = strip * 128 + w * 16 + m16;
  const int* mrow = MASKED ? (mask + ((long)b * SEQLEN + qcol) * SEQLEN + quad * 4) : nullptr;
  float mx = -3.0e38f;
#pragma unroll
  for (int mf = 0; mf < 32; mf++) {
    int4 mm;
    if (MASKED) mm = *(const int4*)(mrow + mf * 16);
#pragma unroll
    for (int r = 0; r < 4; r++) {
      float s = acc[mf][r] * 0.125f;
      if (MASKED) {
        int mv = (r == 0) ? mm.x : (r == 1) ? mm.y : (r == 2) ? mm.z : mm.w;
        if (mv == 0) s = -10000.f;
      }
      acc[mf][r] = s;
      mx = fmaxf(mx, s);
    }
  }
  mx = fmaxf(mx, __shfl_xor(mx, 16));
  mx = fmaxf(mx, __shfl_xor(mx, 32));
  float sum = 0.f;
#pragma unroll
  for (int mf = 0; mf < 32; mf++)
#pragma unroll
    for (int r = 0; r < 4; r++) {
      float e = __expf(acc[mf][r] - mx);
      acc[mf][r] = e;
      sum += e;
    }
  sum += __shfl_xor(sum, 16);
  sum += __shfl_xor(sum, 32);
  const float inv = 1.f / sum;

  // all waves done reading Q/K LDS; Vt must be resident for PV
  __builtin_amdgcn_s_barrier();
  asm volatile("s_waitcnt vmcnt(0)" ::: "memory");

  // ---- PV in two k-halves: P[128 q][256 k] (+8 pad) through LDS ----
  f32x4 o[4];
#pragma unroll
  for (int nf = 0; nf < 4; nf++) o[nf] = f32x4{0.f, 0.f, 0.f, 0.f};

#pragma unroll
  for (int half = 0; half < 2; half++) {
    if (half) {                     // prior PV reads must retire before overwrite
      asm volatile("s_waitcnt lgkmcnt(0)" ::: "memory");
      __builtin_amdgcn_sched_barrier(0);
      __builtin_amdgcn_s_barrier();
    }
    // write this wave's 16 q-rows of P (pack r-pairs -> b32)
#pragma unroll
    for (int mf2 = 0; mf2 < 16; mf2++) {
      const int mf = half * 16 + mf2;
#pragma unroll
      for (int a = 0; a < 2; a++) {
        bf16 lo = (bf16)(acc[mf][2 * a] * inv);
        bf16 hi = (bf16)(acc[mf][2 * a + 1] * inv);
        unsigned u = ((unsigned)*(unsigned short*)&hi << 16) | *(unsigned short*)&lo;
        *(unsigned*)(Psb + qr * 528 + (mf2 * 16 + quad * 4 + 2 * a) * 2) = u;
      }
    }
    asm volatile("s_waitcnt lgkmcnt(0)" ::: "memory");
    __builtin_amdgcn_sched_barrier(0);
    // PV over this half's 8 chunks of 32 k
#pragma unroll
    for (int kb = 0; kb < 8; kb++) {
      bf16x8 pa = *(const bf16x8*)(Psb + qr * 528 + kb * 64 + quad * 16);
#pragma unroll
      for (int nf = 0; nf < 4; nf++) {
        const int vr = nf * 16 + m16;
        bf16x8 vb = *(const bf16x8*)(Vsb + vr * 1024 +
                      ((half * 512 + kb * 64 + quad * 16) ^ ((vr & 7) << 4)));
        o[nf] = __builtin_amdgcn_mfma_f32_16x16x32_bf16(pa, vb, o[nf], 0, 0, 0);
      }
    }
  }

  // ---- O: acc layout [q=quad*4+r][d=16nf+m16] -> LDS transpose -> coalesced ----
  __builtin_amdgcn_s_barrier();    // all Vt reads done before overwriting Vs
#pragma unroll
  for (int nf = 0; nf < 4; nf++)
#pragma unroll
    for (int r = 0; r < 4; r++)
      *(bf16*)(Osb + (w * 16 + quad * 4 + r) * 144 + (nf * 16 + m16) * 2) = (bf16)o[nf][r];
  asm volatile("s_waitcnt lgkmcnt(0)" ::: "memory");
  __builtin_amdgcn_sched_barrier(0);
#pragma unroll
  for (int i2 = 0; i2 < 2; i2++) {
    const int rowL = t >> 2;
    const int d8 = (t & 3) * 16 + i2 * 8;
    bf16x8 v = *(const bf16x8*)(Osb + rowL * 144 + d8 * 2);
    *(bf16x8*)(ob + (qrow0 + rowL) * DMODEL + h * 64 + d8) = v;
  }
}

// ---------------------------------------------------------------------------
// Split-K reduce + bias + residual add + LayerNorm:
// x = LN(h0 + h1 + bias + x) * g + b  (h0,h1 fp32 partials from kgemm256).
// ---------------------------------------------------------------------------
__global__ __launch_bounds__(256) void kaddln2(
    const float* __restrict__ h0, const float* __restrict__ h1,
    const bf16* __restrict__ bias, bf16* __restrict__ x,
    const bf16* __restrict__ g, const bf16* __restrict__ b)
{
  long row = blockIdx.x;
  const float* h0r = h0 + row * DMODEL;
  const float* h1r = h1 + row * DMODEL;
  bf16* xr = x + row * DMODEL;
  int t = threadIdx.x;
  f32x4 a0 = *(const f32x4*)&h0r[t * 4];
  f32x4 a1 = *(const f32x4*)&h1r[t * 4];
  bf16x4 xv = *(const bf16x4*)&xr[t * 4];
  bf16x4 bi = *(const bf16x4*)&bias[t * 4];
  float v[4]; float s1 = 0.f, s2 = 0.f;
#pragma unroll
  for (int i = 0; i < 4; i++) {
    v[i] = a0[i] + a1[i] + (float)bi[i] + (float)xv[i];
    s1 += v[i]; s2 += v[i] * v[i];
  }
#pragma unroll
  for (int off = 32; off > 0; off >>= 1) {
    s1 += __shfl_down(s1, off);
    s2 += __shfl_down(s2, off);
  }
  __shared__ float r1[4], r2[4];
  if ((t & 63) == 0) { r1[t >> 6] = s1; r2[t >> 6] = s2; }
  __syncthreads();
  s1 = r1[0] + r1[1] + r1[2] + r1[3];
  s2 = r2[0] + r2[1] + r2[2] + r2[3];
  float mean = s1 * (1.f / DMODEL);
  float var  = s2 * (1.f / DMODEL) - mean * mean;
  float rstd = rsqrtf(var + 1e-12f);
  bf16x4 gv = *(const bf16x4*)&g[t * 4];
  bf16x4 bv = *(const bf16x4*)&b[t * 4];
  bf16x4 o;
#pragma unroll
  for (int i = 0; i < 4; i++)
    o[i] = (bf16)(((v[i] - mean) * rstd) * (float)gv[i] + (float)bv[i]);
  *(bf16x4*)&xr[t * 4] = o;
}

// ---------------------------------------------------------------------------
extern "C" void kernel_launch(void* const* d_in, const int* in_sizes, int n_in,
                              void* d_out, int out_size, void* d_ws, size_t ws_size,
                              hipStream_t stream)
{
  (void)in_sizes; (void)n_in; (void)out_size; (void)ws_size;
  const void* trg_r  = d_in[0];
  const void* enc_r  = d_in[1];
  const int*  mask   = (const int*)d_in[2];
  const void* sa_w_r = d_in[3];
  const void* sa_b_r = d_in[4];
  const void* ca_w_r = d_in[5];
  const void* ca_b_r = d_in[6];
  const void* ln_g_r = d_in[7];
  const void* ln_b_r = d_in[8];
  const void* w1_r   = d_in[9];
  const void* b1_r   = d_in[10];
  const void* w2_r   = d_in[11];
  const void* b2_r   = d_in[12];

  const size_t XD = (size_t)MTOK * DMODEL;        // 4,194,304 elements
  char* p = (char*)d_ws;
  int*  flag = (int*)p;       p += 256;
  bf16* pSaB = (bf16*)p;      p += (size_t)NLAYER * 4 * DMODEL * 2;
  bf16* pCaB = (bf16*)p;      p += (size_t)NLAYER * 4 * DMODEL * 2;
  bf16* pLnG = (bf16*)p;      p += (size_t)NLAYER * 3 * DMODEL * 2;
  bf16* pLnB = (bf16*)p;      p += (size_t)NLAYER * 3 * DMODEL * 2;
  bf16* pB1  = (bf16*)p;      p += (size_t)NLAYER * FFDIM * 2;
  bf16* pB2  = (bf16*)p;      p += (size_t)NLAYER * DMODEL * 2;
  p = (char*)d_ws + (1 << 20);                                             // 1MB mark
  bf16* x    = (bf16*)p; p += XD * 2;                                      // 8MB
  bf16* encB = (bf16*)p; p += XD * 2;                                      // 8MB
  bf16* qkv  = (bf16*)p; p += (size_t)MTOK * QKVLD * 2;                    // 24MB
  bf16* ob   = (bf16*)p; p += XD * 2;                                      // 8MB
  bf16* hb   = (bf16*)p; p += XD * 2;                                      // 8MB (spare)
  bf16* Vt   = (bf16*)p; p += (size_t)BATCH * NHEAD * DHEAD * SEQLEN * 2;  // 8MB
  bf16* Wt   = (bf16*)p; p += (size_t)4 * DMODEL * DMODEL * 2;             // 8MB
  bf16* big  = (bf16*)p; p += (size_t)BATCH * NHEAD * SEQLEN * SEQLEN * 2; // 64MB
  bf16* ffh  = big;
  (void)hb;
  // fp32 split-K partial buffers (time-share `big`):
  float* Pf  = (float*)big;
  float* PfF = (float*)((char*)big + 33554432);
  const long PZ = (long)MTOK * DMODEL;     // elements per fp32 partial

  const long VS = (long)DHEAD * SEQLEN;    // 32768
  const long PQ = (long)SEQLEN * QKVLD;    // 1572864
  const long DD = (long)DMODEL * DMODEL;   // 1048576

  // --- dtype detection + input conversion ---
  kdetect<<<1, 256, 0, stream>>>((const unsigned short*)trg_r, flag);
  int nb = (int)((XD + 255) / 256);
  kcvt<<<nb, 256, 0, stream>>>(trg_r, x,    (long)XD, flag);
  kcvt<<<nb, 256, 0, stream>>>(enc_r, encB, (long)XD, flag);
  kcvt<<<96,  256, 0, stream>>>(sa_b_r, pSaB, (long)NLAYER * 4 * DMODEL, flag);
  kcvt<<<96,  256, 0, stream>>>(ca_b_r, pCaB, (long)NLAYER * 4 * DMODEL, flag);
  kcvt<<<72,  256, 0, stream>>>(ln_g_r, pLnG, (long)NLAYER * 3 * DMODEL, flag);
  kcvt<<<72,  256, 0, stream>>>(ln_b_r, pLnB, (long)NLAYER * 3 * DMODEL, flag);
  kcvt<<<96,  256, 0, stream>>>(b1_r,   pB1,  (long)NLAYER * FFDIM,      flag);
  kcvt<<<24,  256, 0, stream>>>(b2_r,   pB2,  (long)NLAYER * DMODEL,     flag);
  dim3 tb(32, 8, 1);

  for (int l = 0; l < NLAYER; l++) {
    for (int att = 0; att < 2; att++) {
      const void* Wraw = (att == 0) ? sa_w_r : ca_w_r;
      const bf16* Bv   = ((att == 0) ? pSaB : pCaB) + (size_t)l * 4 * DMODEL;

      // transpose (+convert) 4 weights [K][N] -> Wt[i][N][K]; q|k|v contiguous
      ktranspose<<<dim3(32, 32, 4), tb, 0, stream>>>(
          Wraw, Wt, DMODEL, DMODEL, DMODEL, (long)l * 4 * DD, 0, DD, 4, DD, flag, 1);
      if (att == 0) {
        // fused QKV: [4096,1024] @ [3072,1024]^T -> qkv[4096,3072]
        kgemm256<false, false><<<dim3(16, 12, 1), 512, 0, stream>>>(
            x, Wt, qkv, Bv, 1024, 1024, 1024, QKVLD);
      } else {
        // Q from x (legacy 64x128); K|V fused from enc
        kgemm_nt<64,128,2,2,false><<<dim3(64, 8, 1), 256, 0, stream>>>(
            x, Wt, qkv, Bv, 1024, 1024, 1024, QKVLD, 0,0,0,0,0,0, 1, 1.f);
        kgemm256<false, false><<<dim3(16, 8, 1), 512, 0, stream>>>(
            encB, Wt + DD, qkv + 1024, Bv + 1024, 1024, 1024, 1024, QKVLD);
      }
      // Vt[bh][d][j] = V[bh][j][d]  (before fused attention)
      ktranspose<<<dim3(16, 2, 128), tb, 0, stream>>>(
          qkv + 2048, Vt, SEQLEN, DHEAD, QKVLD, 0, PQ, 64, 16, VS, flag, 0);
      // fused attention: S^T in regs + exact softmax + PV -> ob
      if (att == 0)
        kattn<true><<<dim3(16, 4, 8), 512, 0, stream>>>(qkv, Vt, mask, ob);
      else
        kattn<false><<<dim3(16, 4, 8), 512, 0, stream>>>(qkv, Vt, nullptr, ob);
      // output projection: split-K=2, fp32 partials into Pf
      kgemm256<false, true><<<dim3(16, 4, 2), 512, 0, stream>>>(
          ob, Wt + 3 * DD, Pf, nullptr, 512, 1024, 1024, 1024);
      // x = LN(P0 + P1 + biasO + x)
      kaddln2<<<dim3(MTOK), 256, 0, stream>>>(Pf, Pf + PZ, Bv + 3 * DMODEL, x,
          pLnG + (size_t)(l * 3 + att) * DMODEL, pLnB + (size_t)(l * 3 + att) * DMODEL);
    }

    // ===================== FFN =====================
    ktranspose<<<dim3(32, 128, 1), tb, 0, stream>>>(
        w1_r, Wt, DMODEL, FFDIM, FFDIM, (long)l * DMODEL * FFDIM, 0, 0, 1, 0, flag, 1);
    kgemm256<true, false><<<dim3(16, 16, 1), 512, 0, stream>>>(
        x, Wt, ffh, pB1 + (size_t)l * FFDIM, 1024, 1024, 1024, 4096);
    ktranspose<<<dim3(128, 32, 1), tb, 0, stream>>>(
        w2_r, Wt, FFDIM, DMODEL, DMODEL, (long)l * FFDIM * DMODEL, 0, 0, 1, 0, flag, 1);
    kgemm256<false, true><<<dim3(16, 4, 2), 512, 0, stream>>>(
        ffh, Wt, PfF, nullptr, 2048, 4096, 4096, 1024);
    kaddln2<<<dim3(MTOK), 256, 0, stream>>>(PfF, PfF + PZ, pB2 + (size_t)l * DMODEL, x,
        pLnG + (size_t)(l * 3 + 2) * DMODEL, pLnB + (size_t)(l * 3 + 2) * DMODEL);
  }

  kout<<<nb, 256, 0, stream>>>(x, d_out, (long)XD, flag);
}